// Round 10
// baseline (213.156 us; speedup 1.0000x reference)
//
#include <hip/hip_runtime.h>

#define N_E 10000
#define N_KC 2000
#define ALPHA 0.2f

typedef __attribute__((ext_vector_type(8))) short short8;
typedef __attribute__((ext_vector_type(4))) float f32x4;

// ---- static device scratch (fully rewritten every call) ----
__device__ float g_w1a1[256];
__device__ __align__(16) float g_t[2080];                          // [2000,2080) zero
__device__ unsigned long long g_bm64[N_E * 32];                    // 2.56 MB bitmask
__device__ __align__(16) unsigned short g_W1T_pk[16 * 8 * 512];    // B: W1^T
__device__ __align__(16) unsigned short g_ET_pk[16 * 8 * 512];     // B: E^T
__device__ __align__(16) unsigned short g_rdw_pk[16 * 16 * 512];   // B: rd_w
__device__ __align__(16) unsigned short g_kcWh_pk[16 * 64 * 512];  // B: kcWh^T

__device__ __forceinline__ unsigned short f2bf(float f) {
  union { float f; unsigned int u; } v; v.f = f;
  unsigned int r = v.u + 0x7FFFu + ((v.u >> 16) & 1u);
  return (unsigned short)(r >> 16);
}

__device__ __forceinline__ void cvt_store4(float4 v, unsigned short* dst) {
  ushort4 o;
  o.x = f2bf(v.x); o.y = f2bf(v.y); o.z = f2bf(v.z); o.w = f2bf(v.w);
  *reinterpret_cast<ushort4*>(dst) = o;
}

// ---- prep: weight packing + w1a1 + pads + ballot adj->bitmask ----
__global__ __launch_bounds__(256) void prep_kernel(
    const int* __restrict__ adj, const float* __restrict__ W1,
    const float* __restrict__ E, const float* __restrict__ a,
    const float* __restrict__ rd_w) {
  int b = blockIdx.x, tid = threadIdx.x;
  if (b < 32) {  // rd_w -> packed B (ct 16 x kt 16)
#pragma unroll
    for (int s2 = 0; s2 < 2; ++s2) {
      int sId = b * 512 + tid + s2 * 256;
      int ct = sId >> 10, rem = sId & 1023;
      int kt = rem >> 6, lane = rem & 63;
      int g = lane >> 4, r = lane & 15;
      const float* src = rd_w + (size_t)(ct * 16 + r) * 512 + kt * 32 + g * 8;
      unsigned short* dst = g_rdw_pk + (size_t)sId * 8;
      cvt_store4(*(const float4*)src, dst);
      cvt_store4(*(const float4*)(src + 4), dst + 4);
    }
  } else if (b < 48) {  // W1^T -> packed B
#pragma unroll
    for (int s2 = 0; s2 < 2; ++s2) {
      int sId = (b - 32) * 512 + tid + s2 * 256;
      int ct = sId >> 9, rem = sId & 511;
      int kt = rem >> 6, lane = rem & 63;
      int g = lane >> 4, r = lane & 15;
      int col = ct * 16 + r, k = kt * 32 + g * 8;
      unsigned short* dst = g_W1T_pk + (size_t)sId * 8;
      ushort4 o0, o1;
      o0.x = f2bf(W1[(k + 0) * 256 + col]); o0.y = f2bf(W1[(k + 1) * 256 + col]);
      o0.z = f2bf(W1[(k + 2) * 256 + col]); o0.w = f2bf(W1[(k + 3) * 256 + col]);
      o1.x = f2bf(W1[(k + 4) * 256 + col]); o1.y = f2bf(W1[(k + 5) * 256 + col]);
      o1.z = f2bf(W1[(k + 6) * 256 + col]); o1.w = f2bf(W1[(k + 7) * 256 + col]);
      *(ushort4*)dst = o0; *(ushort4*)(dst + 4) = o1;
    }
  } else if (b < 64) {  // E^T -> packed B
#pragma unroll
    for (int s2 = 0; s2 < 2; ++s2) {
      int sId = (b - 48) * 512 + tid + s2 * 256;
      int ct = sId >> 9, rem = sId & 511;
      int kt = rem >> 6, lane = rem & 63;
      int g = lane >> 4, r = lane & 15;
      int col = ct * 16 + r, k = kt * 32 + g * 8;
      unsigned short* dst = g_ET_pk + (size_t)sId * 8;
      ushort4 o0, o1;
      o0.x = f2bf(E[(k + 0) * 256 + col]); o0.y = f2bf(E[(k + 1) * 256 + col]);
      o0.z = f2bf(E[(k + 2) * 256 + col]); o0.w = f2bf(E[(k + 3) * 256 + col]);
      o1.x = f2bf(E[(k + 4) * 256 + col]); o1.y = f2bf(E[(k + 5) * 256 + col]);
      o1.z = f2bf(E[(k + 6) * 256 + col]); o1.w = f2bf(E[(k + 7) * 256 + col]);
      *(ushort4*)dst = o0; *(ushort4*)(dst + 4) = o1;
    }
  } else if (b == 64) {  // w1a1
    float acc = 0.f;
    for (int q = 0; q < 64; ++q) {
      float4 wv = *(const float4*)(W1 + (size_t)tid * 256 + q * 4);
      float4 a4 = *(const float4*)(a + q * 4);
      acc += wv.x * a4.x + wv.y * a4.y + wv.z * a4.z + wv.w * a4.w;
    }
    g_w1a1[tid] = acc;
  } else if (b == 65) {  // pads: kcWh kt 62/63 zero + g_t zero (t uses atomics)
    for (int idx = tid; idx < 16 * 2 * 512; idx += 256) {
      int ct = idx >> 10, rem = idx & 1023;
      int kt = 62 + (rem >> 9), off = rem & 511;
      g_kcWh_pk[((size_t)ct * 64 + kt) * 512 + off] = 0;
    }
    for (int idx = tid; idx < 2080; idx += 256) g_t[idx] = 0.f;
  } else {  // b in [66, 2566): adj -> bitmask, 4 rows/block via ballot
    int w = tid >> 6, lane = tid & 63;
    int row = (b - 66) * 4 + w;
    const int* ap = adj + (size_t)row * N_KC;
#pragma unroll 4
    for (int q = 0; q < 32; ++q) {
      int c = q * 64 + lane;
      int v = (c < N_KC) ? ap[c] : 0;
      unsigned long long m = __ballot(v > 0);
      if (lane == 0) g_bm64[(size_t)row * 32 + q] = m;
    }
  }
}

// ---- kcWh^T via MFMA (500 blocks) + t partials via atomicAdd ----
__global__ __launch_bounds__(256) void kc_mfma_kernel(
    const float* __restrict__ kc_h, const float* __restrict__ a) {
  int tid = threadIdx.x, lane = tid & 63, w = tid >> 6;
  int r = lane & 15, g = lane >> 4;
  int j0 = (blockIdx.x >> 2) * 16;
  int ct = (blockIdx.x & 3) * 4 + w;
  f32x4 acc = {0.f, 0.f, 0.f, 0.f};
  for (int kk = 0; kk < 8; ++kk) {
    int k = kk * 32 + g * 8;
    const float* src = kc_h + (size_t)(j0 + r) * 256 + k;
    float4 x0 = *(const float4*)src, x1 = *(const float4*)(src + 4);
    short8 af = {(short)f2bf(x0.x), (short)f2bf(x0.y), (short)f2bf(x0.z),
                 (short)f2bf(x0.w), (short)f2bf(x1.x), (short)f2bf(x1.y),
                 (short)f2bf(x1.z), (short)f2bf(x1.w)};
    short8 bf = *(const short8*)(g_W1T_pk + ((size_t)ct * 8 + kk) * 512 +
                                 lane * 8);
    acc = __builtin_amdgcn_mfma_f32_16x16x32_bf16(af, bf, acc, 0, 0, 0);
  }
  // packed store of kcWh^T fragment
  int j = j0 + g * 4;
  int kt = j >> 5, lsub = ((j >> 3) & 3) * 16 + r, sub = (g & 1) * 4;
  ushort4 o;
  o.x = f2bf(acc[0]); o.y = f2bf(acc[1]); o.z = f2bf(acc[2]); o.w = f2bf(acc[3]);
  *reinterpret_cast<ushort4*>(
      g_kcWh_pk + ((size_t)ct * 64 + kt) * 512 + lsub * 8 + sub) = o;
  // t partial: sum over this ct's 16 cols
  float a2v = a[256 + ct * 16 + r];
  float tp[4];
#pragma unroll
  for (int q = 0; q < 4; ++q) tp[q] = acc[q] * a2v;
#pragma unroll
  for (int off = 1; off < 16; off <<= 1)
#pragma unroll
    for (int q = 0; q < 4; ++q) tp[q] += __shfl_xor(tp[q], off, 64);
  if (r == 0)
#pragma unroll
    for (int q = 0; q < 4; ++q) atomicAdd(&g_t[j0 + g * 4 + q], tp[q]);
}

// ---- main: bitmask P-gen pipeline + fused 3 MFMA GEMMs ----
#define PST 280
#define FST 536
__global__ __launch_bounds__(512, 4) void main_kernel(
    const float* __restrict__ exh, const float* __restrict__ rd_b,
    float* __restrict__ out) {
  __shared__ __align__(16) float t_s[2080];
  __shared__ unsigned long long bm_s[16 * 33];
  __shared__ __align__(16) unsigned short p_s[2][16 * PST];
  __shared__ __align__(16) unsigned short feat_s[16 * FST];  // union: exh frags
  __shared__ float ds_part[8][16];
  __shared__ float red16[16];

  int tid = threadIdx.x, w = tid >> 6, lane = tid & 63;
  int r = lane & 15, g = lane >> 4;
  int i0 = blockIdx.x * 16;
  unsigned short* exh_pk_s = feat_s;  // [kt*512 + lane*8], 8 KB

  // ---- phase 0: stage t, bitmask, exh frags; s = exh·w1a1 ----
  for (int q = tid; q < 520; q += 512)
    ((float4*)t_s)[q] = ((const float4*)g_t)[q];
  {
    int rr = tid >> 5, wd = tid & 31;
    bm_s[rr * 33 + wd] = g_bm64[(size_t)(i0 + rr) * 32 + wd];
    if (tid < 16) bm_s[tid * 33 + 32] = 0ull;
  }
  {
    const float* xsrc = exh + (size_t)(i0 + r) * 256 + w * 32 + g * 8;
    float4 x0 = *(const float4*)xsrc, x1 = *(const float4*)(xsrc + 4);
    unsigned short* dst = exh_pk_s + w * 512 + lane * 8;
    cvt_store4(x0, dst); cvt_store4(x1, dst + 4);
    const float* wsrc = g_w1a1 + w * 32 + g * 8;
    float4 w0 = *(const float4*)wsrc, w1 = *(const float4*)(wsrc + 4);
    float sp = x0.x * w0.x + x0.y * w0.y + x0.z * w0.z + x0.w * w0.w +
               x1.x * w1.x + x1.y * w1.y + x1.z * w1.z + x1.w * w1.w;
    sp += __shfl_xor(sp, 16, 64);
    sp += __shfl_xor(sp, 32, 64);
    if (lane < 16) ds_part[w][lane] = sp;
  }
  __syncthreads();
  if (tid < 16) {
    float sv = 0.f;
#pragma unroll
    for (int ww = 0; ww < 8; ++ww) sv += ds_part[ww][tid];
    red16[tid] = sv;
  }
  __syncthreads();
  float sv = red16[r];

  f32x4 accP[2] = {{0.f,0.f,0.f,0.f},{0.f,0.f,0.f,0.f}};
  f32x4 accE[2] = {{0.f,0.f,0.f,0.f},{0.f,0.f,0.f,0.f}};
  float dsum = 0.f;

  // gen: wave w produces P rows for kk = c*8 + w (32 cols x 16 rows)
  auto gen = [&](int c) {
    int kk = c * 8 + w;
    int c0 = kk * 32 + g * 8;
    unsigned mb = (unsigned)((bm_s[r * 33 + (c0 >> 6)] >> (c0 & 63)) & 0xFFull);
    float4 t0 = *(const float4*)(t_s + c0);
    float4 t1 = *(const float4*)(t_s + c0 + 4);
    float tv[8] = {t0.x, t0.y, t0.z, t0.w, t1.x, t1.y, t1.z, t1.w};
    unsigned ub[8];
#pragma unroll
    for (int j = 0; j < 8; ++j) {
      float x = sv + tv[j];
      float lx = fmaxf(x, ALPHA * x);
      float pv = ((mb >> j) & 1u) ? __expf(lx) : 0.f;
      dsum += pv;
      ub[j] = __float_as_uint(pv) + 0x8000u;
    }
    int4 pk;
    pk.x = (int)((ub[0] >> 16) | (ub[1] & 0xFFFF0000u));
    pk.y = (int)((ub[2] >> 16) | (ub[3] & 0xFFFF0000u));
    pk.z = (int)((ub[4] >> 16) | (ub[5] & 0xFFFF0000u));
    pk.w = (int)((ub[6] >> 16) | (ub[7] & 0xFFFF0000u));
    *(int4*)&p_s[c & 1][r * PST + w * 32 + g * 8] = pk;
  };

  // mfma for chunk c's P + fused ex_Eh kk=c (fills gen-stall bubbles)
  auto mfma_chunk = [&](int c) {
    const unsigned short* pb = p_s[c & 1];
    const unsigned short* bb0 =
        g_kcWh_pk + ((size_t)(w * 2 + 0) * 64 + c * 8) * 512 + lane * 8;
    const unsigned short* bb1 =
        g_kcWh_pk + ((size_t)(w * 2 + 1) * 64 + c * 8) * 512 + lane * 8;
    short8 af = *(const short8*)&pb[r * PST + g * 8];
    short8 b0 = *(const short8*)bb0;
    short8 b1 = *(const short8*)bb1;
#pragma unroll
    for (int u = 0; u < 8; ++u) {
      short8 naf = af, nb0 = b0, nb1 = b1;
      if (u < 7) {
        naf = *(const short8*)&pb[r * PST + (u + 1) * 32 + g * 8];
        nb0 = *(const short8*)(bb0 + (u + 1) * 512);
        nb1 = *(const short8*)(bb1 + (u + 1) * 512);
      }
      accP[0] = __builtin_amdgcn_mfma_f32_16x16x32_bf16(af, b0, accP[0], 0, 0, 0);
      accP[1] = __builtin_amdgcn_mfma_f32_16x16x32_bf16(af, b1, accP[1], 0, 0, 0);
      af = naf; b0 = nb0; b1 = nb1;
    }
    short8 ae = *(const short8*)(exh_pk_s + c * 512 + lane * 8);
#pragma unroll
    for (int n = 0; n < 2; ++n) {
      short8 be = *(const short8*)(g_ET_pk + ((size_t)(w * 2 + n) * 8 + c) *
                                                 512 + lane * 8);
      accE[n] = __builtin_amdgcn_mfma_f32_16x16x32_bf16(ae, be, accE[n], 0, 0, 0);
    }
  };

  gen(0);
  __syncthreads();
  for (int c = 1; c < 8; ++c) {
    gen(c);
    mfma_chunk(c - 1);
    __syncthreads();
  }
  mfma_chunk(7);

  // denominator
  dsum += __shfl_xor(dsum, 16, 64);
  dsum += __shfl_xor(dsum, 32, 64);
  if (lane < 16) ds_part[w][lane] = dsum;
  __syncthreads();
  if (tid < 16) {
    float s = 0.f;
#pragma unroll
    for (int ww = 0; ww < 8; ++ww) s += ds_part[ww][tid];
    red16[tid] = 1.f / fmaxf(s, 1e-30f);
  }
  __syncthreads();

  // feat = [new_kc | new_kc * ex_Eh]  (overwrites exh frag region)
  int c0e = w * 32;
#pragma unroll
  for (int n = 0; n < 2; ++n) {
    int col = c0e + n * 16 + r;
#pragma unroll
    for (int q = 0; q < 4; ++q) {
      int row = g * 4 + q;
      float nk = accP[n][q] * red16[row];
      feat_s[row * FST + col] = f2bf(nk);
      feat_s[row * FST + 256 + col] = f2bf(nk * accE[n][q]);
    }
  }
  __syncthreads();

  // epilogue GEMM: feat(16x512) @ rd_w^T + bias, ELU
  f32x4 accO[2] = {{0.f,0.f,0.f,0.f},{0.f,0.f,0.f,0.f}};
#pragma unroll
  for (int kk = 0; kk < 16; ++kk) {
    int k = kk * 32 + g * 8;
    short8 af = *(const short8*)&feat_s[r * FST + k];
#pragma unroll
    for (int n = 0; n < 2; ++n) {
      short8 bf = *(const short8*)(g_rdw_pk + ((size_t)(w * 2 + n) * 16 + kk) *
                                                  512 + lane * 8);
      accO[n] = __builtin_amdgcn_mfma_f32_16x16x32_bf16(af, bf, accO[n], 0, 0, 0);
    }
  }
#pragma unroll
  for (int n = 0; n < 2; ++n) {
    int col = c0e + n * 16 + r;
    float bias = rd_b[col];
#pragma unroll
    for (int q = 0; q < 4; ++q) {
      int row = g * 4 + q;
      float x = accO[n][q] + bias;
      float res = x > 0.f ? x : (__expf(x) - 1.f);
      out[(size_t)(i0 + row) * 256 + col] = res;
    }
  }
}

extern "C" void kernel_launch(void* const* d_in, const int* in_sizes, int n_in,
                              void* d_out, int out_size, void* d_ws,
                              size_t ws_size, hipStream_t stream) {
  const float* exh  = (const float*)d_in[0];
  const float* kc_h = (const float*)d_in[1];
  const int*   adj  = (const int*)d_in[2];
  const float* W1   = (const float*)d_in[3];
  const float* E    = (const float*)d_in[4];
  const float* a    = (const float*)d_in[5];
  const float* rd_w = (const float*)d_in[6];
  const float* rd_b = (const float*)d_in[7];
  float* out = (float*)d_out;

  prep_kernel<<<2566, 256, 0, stream>>>(adj, W1, E, a, rd_w);
  kc_mfma_kernel<<<500, 256, 0, stream>>>(kc_h, a);
  main_kernel<<<N_E / 16, 512, 0, stream>>>(exh, rd_b, out);
}

// Round 11
// 187.323 us; speedup vs baseline: 1.1379x; 1.1379x over previous
//
#include <hip/hip_runtime.h>

#define N_E 10000
#define N_KC 2000
#define ALPHA 0.2f

typedef __attribute__((ext_vector_type(8))) short short8;
typedef __attribute__((ext_vector_type(4))) float f32x4;

// ---- static device scratch (fully rewritten every call) ----
__device__ float g_w1a1[256];
__device__ __align__(16) float g_t[2080];                          // [2000,2080) zero
__device__ unsigned long long g_bm64[N_E * 32];                    // 2.56 MB bitmask
__device__ __align__(16) unsigned short g_W1T_pk[16 * 8 * 512];    // B: W1^T
__device__ __align__(16) unsigned short g_ET_pk[16 * 8 * 512];     // B: E^T
__device__ __align__(16) unsigned short g_rdw_pk[16 * 16 * 512];   // B: rd_w
__device__ __align__(16) unsigned short g_kcWh_pk[16 * 64 * 512];  // B: kcWh^T

__device__ __forceinline__ unsigned short f2bf(float f) {
  union { float f; unsigned int u; } v; v.f = f;
  unsigned int r = v.u + 0x7FFFu + ((v.u >> 16) & 1u);
  return (unsigned short)(r >> 16);
}

__device__ __forceinline__ void cvt_store4(float4 v, unsigned short* dst) {
  ushort4 o;
  o.x = f2bf(v.x); o.y = f2bf(v.y); o.z = f2bf(v.z); o.w = f2bf(v.w);
  *reinterpret_cast<ushort4*>(dst) = o;
}

// spread 16 bits so source bit i lands at position 4i
__device__ __forceinline__ unsigned long long spread4(unsigned long long x) {
  x &= 0xFFFFull;
  x = (x | (x << 24)) & 0x000000FF000000FFull;
  x = (x | (x << 12)) & 0x000F000F000F000Full;
  x = (x | (x << 6))  & 0x0303030303030303ull;
  x = (x | (x << 3))  & 0x1111111111111111ull;
  return x;
}

// ---- prep: weight packing + w1a1 + pads + fast adj->bitmask ----
__global__ __launch_bounds__(256) void prep_kernel(
    const int* __restrict__ adj, const float* __restrict__ W1,
    const float* __restrict__ E, const float* __restrict__ a,
    const float* __restrict__ rd_w) {
  int b = blockIdx.x, tid = threadIdx.x;
  if (b < 32) {  // rd_w -> packed B (ct 16 x kt 16)
#pragma unroll
    for (int s2 = 0; s2 < 2; ++s2) {
      int sId = b * 512 + tid + s2 * 256;
      int ct = sId >> 10, rem = sId & 1023;
      int kt = rem >> 6, lane = rem & 63;
      int g = lane >> 4, r = lane & 15;
      const float* src = rd_w + (size_t)(ct * 16 + r) * 512 + kt * 32 + g * 8;
      unsigned short* dst = g_rdw_pk + (size_t)sId * 8;
      cvt_store4(*(const float4*)src, dst);
      cvt_store4(*(const float4*)(src + 4), dst + 4);
    }
  } else if (b < 48) {  // W1^T -> packed B
#pragma unroll
    for (int s2 = 0; s2 < 2; ++s2) {
      int sId = (b - 32) * 512 + tid + s2 * 256;
      int ct = sId >> 9, rem = sId & 511;
      int kt = rem >> 6, lane = rem & 63;
      int g = lane >> 4, r = lane & 15;
      int col = ct * 16 + r, k = kt * 32 + g * 8;
      unsigned short* dst = g_W1T_pk + (size_t)sId * 8;
      ushort4 o0, o1;
      o0.x = f2bf(W1[(k + 0) * 256 + col]); o0.y = f2bf(W1[(k + 1) * 256 + col]);
      o0.z = f2bf(W1[(k + 2) * 256 + col]); o0.w = f2bf(W1[(k + 3) * 256 + col]);
      o1.x = f2bf(W1[(k + 4) * 256 + col]); o1.y = f2bf(W1[(k + 5) * 256 + col]);
      o1.z = f2bf(W1[(k + 6) * 256 + col]); o1.w = f2bf(W1[(k + 7) * 256 + col]);
      *(ushort4*)dst = o0; *(ushort4*)(dst + 4) = o1;
    }
  } else if (b < 64) {  // E^T -> packed B
#pragma unroll
    for (int s2 = 0; s2 < 2; ++s2) {
      int sId = (b - 48) * 512 + tid + s2 * 256;
      int ct = sId >> 9, rem = sId & 511;
      int kt = rem >> 6, lane = rem & 63;
      int g = lane >> 4, r = lane & 15;
      int col = ct * 16 + r, k = kt * 32 + g * 8;
      unsigned short* dst = g_ET_pk + (size_t)sId * 8;
      ushort4 o0, o1;
      o0.x = f2bf(E[(k + 0) * 256 + col]); o0.y = f2bf(E[(k + 1) * 256 + col]);
      o0.z = f2bf(E[(k + 2) * 256 + col]); o0.w = f2bf(E[(k + 3) * 256 + col]);
      o1.x = f2bf(E[(k + 4) * 256 + col]); o1.y = f2bf(E[(k + 5) * 256 + col]);
      o1.z = f2bf(E[(k + 6) * 256 + col]); o1.w = f2bf(E[(k + 7) * 256 + col]);
      *(ushort4*)dst = o0; *(ushort4*)(dst + 4) = o1;
    }
  } else if (b == 64) {  // w1a1
    float acc = 0.f;
    for (int q = 0; q < 64; ++q) {
      float4 wv = *(const float4*)(W1 + (size_t)tid * 256 + q * 4);
      float4 a4 = *(const float4*)(a + q * 4);
      acc += wv.x * a4.x + wv.y * a4.y + wv.z * a4.z + wv.w * a4.w;
    }
    g_w1a1[tid] = acc;
  } else if (b == 65) {  // pads: kcWh kt 62/63 zero + g_t zero (t uses atomics)
    for (int idx = tid; idx < 16 * 2 * 512; idx += 256) {
      int ct = idx >> 10, rem = idx & 1023;
      int kt = 62 + (rem >> 9), off = rem & 511;
      g_kcWh_pk[((size_t)ct * 64 + kt) * 512 + off] = 0;
    }
    for (int idx = tid; idx < 2080; idx += 256) g_t[idx] = 0.f;
  } else {  // adj -> bitmask: int4 + 4 ballots + Morton spread, 4 rows/block
    int w = tid >> 6, lane = tid & 63;
    int row = (b - 66) * 4 + w;
    const int* ap = adj + (size_t)row * N_KC;
#pragma unroll
    for (int it = 0; it < 8; ++it) {
      int c0 = it * 256 + lane * 4;
      int4 v = {0, 0, 0, 0};
      if (c0 < N_KC) v = *(const int4*)(ap + c0);  // 2000 % 4 == 0
      unsigned long long m0 = __ballot(v.x > 0);
      unsigned long long m1 = __ballot(v.y > 0);
      unsigned long long m2 = __ballot(v.z > 0);
      unsigned long long m3 = __ballot(v.w > 0);
      if (lane < 4) {
        int sh = lane * 16;
        unsigned long long W = spread4(m0 >> sh) | (spread4(m1 >> sh) << 1) |
                               (spread4(m2 >> sh) << 2) | (spread4(m3 >> sh) << 3);
        g_bm64[(size_t)row * 32 + it * 4 + lane] = W;
      }
    }
  }
}

// ---- kcWh^T via MFMA (500 blocks) + t partials via atomicAdd ----
__global__ __launch_bounds__(256) void kc_mfma_kernel(
    const float* __restrict__ kc_h, const float* __restrict__ a) {
  int tid = threadIdx.x, lane = tid & 63, w = tid >> 6;
  int r = lane & 15, g = lane >> 4;
  int j0 = (blockIdx.x >> 2) * 16;
  int ct = (blockIdx.x & 3) * 4 + w;
  f32x4 acc = {0.f, 0.f, 0.f, 0.f};
  for (int kk = 0; kk < 8; ++kk) {
    int k = kk * 32 + g * 8;
    const float* src = kc_h + (size_t)(j0 + r) * 256 + k;
    float4 x0 = *(const float4*)src, x1 = *(const float4*)(src + 4);
    short8 af = {(short)f2bf(x0.x), (short)f2bf(x0.y), (short)f2bf(x0.z),
                 (short)f2bf(x0.w), (short)f2bf(x1.x), (short)f2bf(x1.y),
                 (short)f2bf(x1.z), (short)f2bf(x1.w)};
    short8 bf = *(const short8*)(g_W1T_pk + ((size_t)ct * 8 + kk) * 512 +
                                 lane * 8);
    acc = __builtin_amdgcn_mfma_f32_16x16x32_bf16(af, bf, acc, 0, 0, 0);
  }
  int j = j0 + g * 4;
  int kt = j >> 5, lsub = ((j >> 3) & 3) * 16 + r, sub = (g & 1) * 4;
  ushort4 o;
  o.x = f2bf(acc[0]); o.y = f2bf(acc[1]); o.z = f2bf(acc[2]); o.w = f2bf(acc[3]);
  *reinterpret_cast<ushort4*>(
      g_kcWh_pk + ((size_t)ct * 64 + kt) * 512 + lsub * 8 + sub) = o;
  float a2v = a[256 + ct * 16 + r];
  float tp[4];
#pragma unroll
  for (int q = 0; q < 4; ++q) tp[q] = acc[q] * a2v;
#pragma unroll
  for (int off = 1; off < 16; off <<= 1)
#pragma unroll
    for (int q = 0; q < 4; ++q) tp[q] += __shfl_xor(tp[q], off, 64);
  if (r == 0)
#pragma unroll
    for (int q = 0; q < 4; ++q) atomicAdd(&g_t[j0 + g * 4 + q], tp[q]);
}

// ---- main: TR=32, bitmask P-gen pipeline + fused 3 MFMA GEMMs ----
#define PSTR 136
#define FST 536
__global__ __launch_bounds__(512, 4) void main_kernel(
    const float* __restrict__ exh, const float* __restrict__ rd_b,
    float* __restrict__ out) {
  __shared__ __align__(16) unsigned char smem[50816];
  __shared__ float ds_part[8][32];
  __shared__ float red32[32];
  float* t_s = (float*)smem;                                       // 8320 B
  unsigned long long* bm_s = (unsigned long long*)(smem + 8320);   // 32*34*8
  unsigned short* p_s = (unsigned short*)(smem + 17024);           // [2][32][136]
  unsigned short* exh_pk_s = (unsigned short*)(smem + 34432);      // [2][4096]
  unsigned short* feat_s = (unsigned short*)smem;                  // [32][536] late

  int tid = threadIdx.x, w = tid >> 6, lane = tid & 63;
  int r = lane & 15, g = lane >> 4;
  int i0 = blockIdx.x * 32;
  int mh = w >> 2, kw = w & 3;

  // ---- phase 0: stage t, bitmask, exh frags; s = exh·w1a1 ----
  for (int q = tid; q < 520; q += 512)
    ((float4*)t_s)[q] = ((const float4*)g_t)[q];
  for (int q = tid; q < 32 * 32; q += 512) {
    int rr = q >> 5, wd = q & 31;
    int grow = i0 + rr; grow = grow < N_E ? grow : N_E - 1;
    bm_s[rr * 34 + wd] = g_bm64[(size_t)grow * 32 + wd];
  }
  {
    const float* wsrc = g_w1a1 + w * 32 + g * 8;
    float4 w0 = *(const float4*)wsrc, w1 = *(const float4*)(wsrc + 4);
    float sp[2];
#pragma unroll
    for (int m = 0; m < 2; ++m) {
      int row = i0 + m * 16 + r; row = row < N_E ? row : N_E - 1;
      const float* xsrc = exh + (size_t)row * 256 + w * 32 + g * 8;
      float4 x0 = *(const float4*)xsrc, x1 = *(const float4*)(xsrc + 4);
      unsigned short* dst = exh_pk_s + m * 4096 + w * 512 + lane * 8;
      cvt_store4(x0, dst); cvt_store4(x1, dst + 4);
      sp[m] = x0.x * w0.x + x0.y * w0.y + x0.z * w0.z + x0.w * w0.w +
              x1.x * w1.x + x1.y * w1.y + x1.z * w1.z + x1.w * w1.w;
      sp[m] += __shfl_xor(sp[m], 16, 64);
      sp[m] += __shfl_xor(sp[m], 32, 64);
    }
    if (lane < 16) { ds_part[w][lane] = sp[0]; ds_part[w][16 + lane] = sp[1]; }
  }
  __syncthreads();
  if (tid < 32) {
    float sv = 0.f;
#pragma unroll
    for (int ww = 0; ww < 8; ++ww) sv += ds_part[ww][tid];
    red32[tid] = sv;
  }
  __syncthreads();
  float sv = red32[mh * 16 + r];

  f32x4 accP[2][2] = {{{0.f,0.f,0.f,0.f},{0.f,0.f,0.f,0.f}},
                      {{0.f,0.f,0.f,0.f},{0.f,0.f,0.f,0.f}}};
  f32x4 accE[2][2] = {{{0.f,0.f,0.f,0.f},{0.f,0.f,0.f,0.f}},
                      {{0.f,0.f,0.f,0.f},{0.f,0.f,0.f,0.f}}};
  float dsum = 0.f;

  // gen: wave (mh,kw) fills rows [mh*16,+16), kk = c*4+kw (all kk<64 valid)
  auto gen = [&](int c) {
    int kk = c * 4 + kw;
    int c0 = kk * 32 + g * 8;
    unsigned mb =
        (unsigned)((bm_s[(mh * 16 + r) * 34 + (c0 >> 6)] >> (c0 & 63)) & 0xFFull);
    float4 t0 = *(const float4*)(t_s + c0);
    float4 t1 = *(const float4*)(t_s + c0 + 4);
    float tv[8] = {t0.x, t0.y, t0.z, t0.w, t1.x, t1.y, t1.z, t1.w};
    unsigned ub[8];
#pragma unroll
    for (int j = 0; j < 8; ++j) {
      float x = sv + tv[j];
      float lx = fmaxf(x, ALPHA * x);
      float pv = ((mb >> j) & 1u) ? __expf(lx) : 0.f;
      dsum += pv;
      ub[j] = __float_as_uint(pv) + 0x8000u;
    }
    int4 pk;
    pk.x = (int)((ub[0] >> 16) | (ub[1] & 0xFFFF0000u));
    pk.y = (int)((ub[2] >> 16) | (ub[3] & 0xFFFF0000u));
    pk.z = (int)((ub[4] >> 16) | (ub[5] & 0xFFFF0000u));
    pk.w = (int)((ub[6] >> 16) | (ub[7] & 0xFFFF0000u));
    *(int4*)(p_s + ((size_t)(c & 1) * 32 + mh * 16 + r) * PSTR + kw * 32 +
             g * 8) = pk;
  };

  auto mfma_chunk = [&](int c) {
    const unsigned short* pb = p_s + (size_t)(c & 1) * 32 * PSTR;
    const unsigned short* bb0 =
        g_kcWh_pk + ((size_t)(w * 2 + 0) * 64 + c * 4) * 512 + lane * 8;
    const unsigned short* bb1 =
        g_kcWh_pk + ((size_t)(w * 2 + 1) * 64 + c * 4) * 512 + lane * 8;
    short8 b0 = *(const short8*)bb0;
    short8 b1 = *(const short8*)bb1;
#pragma unroll
    for (int u = 0; u < 4; ++u) {
      short8 a0 = *(const short8*)(pb + (size_t)r * PSTR + u * 32 + g * 8);
      short8 a1 = *(const short8*)(pb + (size_t)(16 + r) * PSTR + u * 32 + g * 8);
      short8 nb0 = b0, nb1 = b1;
      if (u < 3) {
        nb0 = *(const short8*)(bb0 + (u + 1) * 512);
        nb1 = *(const short8*)(bb1 + (u + 1) * 512);
      }
      accP[0][0] = __builtin_amdgcn_mfma_f32_16x16x32_bf16(a0, b0, accP[0][0], 0, 0, 0);
      accP[1][0] = __builtin_amdgcn_mfma_f32_16x16x32_bf16(a1, b0, accP[1][0], 0, 0, 0);
      accP[0][1] = __builtin_amdgcn_mfma_f32_16x16x32_bf16(a0, b1, accP[0][1], 0, 0, 0);
      accP[1][1] = __builtin_amdgcn_mfma_f32_16x16x32_bf16(a1, b1, accP[1][1], 0, 0, 0);
      b0 = nb0; b1 = nb1;
    }
    if ((c & 1) == 0) {  // fused ex_Eh kt = c/2
      int ke = c >> 1;
      short8 a0 = *(const short8*)(exh_pk_s + ke * 512 + lane * 8);
      short8 a1 = *(const short8*)(exh_pk_s + 4096 + ke * 512 + lane * 8);
#pragma unroll
      for (int n = 0; n < 2; ++n) {
        short8 be = *(const short8*)(g_ET_pk + ((size_t)(w * 2 + n) * 8 + ke) *
                                                   512 + lane * 8);
        accE[0][n] = __builtin_amdgcn_mfma_f32_16x16x32_bf16(a0, be, accE[0][n], 0, 0, 0);
        accE[1][n] = __builtin_amdgcn_mfma_f32_16x16x32_bf16(a1, be, accE[1][n], 0, 0, 0);
      }
    }
  };

  gen(0);
  __syncthreads();
  for (int c = 1; c < 16; ++c) {
    gen(c);
    mfma_chunk(c - 1);
    __syncthreads();
  }
  mfma_chunk(15);

  // denominator (wave covers its row-half; zero the other)
  dsum += __shfl_xor(dsum, 16, 64);
  dsum += __shfl_xor(dsum, 32, 64);
  if (lane < 16) {
    ds_part[w][mh * 16 + lane] = dsum;
    ds_part[w][(1 - mh) * 16 + lane] = 0.f;
  }
  __syncthreads();
  if (tid < 32) {
    float s = 0.f;
#pragma unroll
    for (int ww = 0; ww < 8; ++ww) s += ds_part[ww][tid];
    red32[tid] = 1.f / fmaxf(s, 1e-30f);
  }
  __syncthreads();

  // feat = [new_kc | new_kc * ex_Eh] (overlays t/bm/p region)
  int c0e = w * 32;
#pragma unroll
  for (int m = 0; m < 2; ++m)
#pragma unroll
    for (int n = 0; n < 2; ++n) {
      int col = c0e + n * 16 + r;
#pragma unroll
      for (int q = 0; q < 4; ++q) {
        int row = m * 16 + g * 4 + q;
        float nk = accP[m][n][q] * red32[row];
        feat_s[(size_t)row * FST + col] = f2bf(nk);
        feat_s[(size_t)row * FST + 256 + col] = f2bf(nk * accE[m][n][q]);
      }
    }
  __syncthreads();

  // epilogue GEMM: feat(32x512) @ rd_w^T + bias, ELU
  f32x4 accO[2][2] = {{{0.f,0.f,0.f,0.f},{0.f,0.f,0.f,0.f}},
                      {{0.f,0.f,0.f,0.f},{0.f,0.f,0.f,0.f}}};
#pragma unroll
  for (int kt = 0; kt < 16; ++kt) {
    int k = kt * 32 + g * 8;
    short8 a0 = *(const short8*)(feat_s + (size_t)r * FST + k);
    short8 a1 = *(const short8*)(feat_s + (size_t)(16 + r) * FST + k);
#pragma unroll
    for (int n = 0; n < 2; ++n) {
      short8 bf = *(const short8*)(g_rdw_pk + ((size_t)(w * 2 + n) * 16 + kt) *
                                                  512 + lane * 8);
      accO[0][n] = __builtin_amdgcn_mfma_f32_16x16x32_bf16(a0, bf, accO[0][n], 0, 0, 0);
      accO[1][n] = __builtin_amdgcn_mfma_f32_16x16x32_bf16(a1, bf, accO[1][n], 0, 0, 0);
    }
  }
#pragma unroll
  for (int m = 0; m < 2; ++m) {
    if (i0 + m * 16 >= N_E) continue;
#pragma unroll
    for (int n = 0; n < 2; ++n) {
      int col = c0e + n * 16 + r;
      float bias = rd_b[col];
#pragma unroll
      for (int q = 0; q < 4; ++q) {
        int row = i0 + m * 16 + g * 4 + q;
        float x = accO[m][n][q] + bias;
        float res = x > 0.f ? x : (__expf(x) - 1.f);
        out[(size_t)row * 256 + col] = res;
      }
    }
  }
}

extern "C" void kernel_launch(void* const* d_in, const int* in_sizes, int n_in,
                              void* d_out, int out_size, void* d_ws,
                              size_t ws_size, hipStream_t stream) {
  const float* exh  = (const float*)d_in[0];
  const float* kc_h = (const float*)d_in[1];
  const int*   adj  = (const int*)d_in[2];
  const float* W1   = (const float*)d_in[3];
  const float* E    = (const float*)d_in[4];
  const float* a    = (const float*)d_in[5];
  const float* rd_w = (const float*)d_in[6];
  const float* rd_b = (const float*)d_in[7];
  float* out = (float*)d_out;

  prep_kernel<<<2566, 256, 0, stream>>>(adj, W1, E, a, rd_w);
  kc_mfma_kernel<<<500, 256, 0, stream>>>(kc_h, a);
  main_kernel<<<(N_E + 31) / 32, 512, 0, stream>>>(exh, rd_b, out);
}

// Round 13
// 184.274 us; speedup vs baseline: 1.1567x; 1.0165x over previous
//
#include <hip/hip_runtime.h>

#define N_E 10000
#define N_KC 2000
#define ALPHA 0.2f

typedef __attribute__((ext_vector_type(8))) short short8;
typedef __attribute__((ext_vector_type(4))) float f32x4;

// ---- static device scratch (fully rewritten every call) ----
__device__ float g_w1a1[256];
__device__ __align__(16) float g_t_part[4][2000];                  // t partials
__device__ unsigned long long g_bm64[N_E * 32];                    // 2.56 MB bitmask
__device__ __align__(16) unsigned short g_ET_pk[16 * 8 * 512];     // B: E^T
__device__ __align__(16) unsigned short g_rdw_pk[16 * 16 * 512];   // B: rd_w
__device__ __align__(16) unsigned short g_kcWh_pk[16 * 64 * 512];  // B: kcWh^T

__device__ __forceinline__ unsigned short f2bf(float f) {
  union { float f; unsigned int u; } v; v.f = f;
  unsigned int r = v.u + 0x7FFFu + ((v.u >> 16) & 1u);
  return (unsigned short)(r >> 16);
}

__device__ __forceinline__ void cvt_store4(float4 v, unsigned short* dst) {
  ushort4 o;
  o.x = f2bf(v.x); o.y = f2bf(v.y); o.z = f2bf(v.z); o.w = f2bf(v.w);
  *reinterpret_cast<ushort4*>(dst) = o;
}

// spread 16 bits so source bit i lands at position 4i
__device__ __forceinline__ unsigned long long spread4(unsigned long long x) {
  x &= 0xFFFFull;
  x = (x | (x << 24)) & 0x000000FF000000FFull;
  x = (x | (x << 12)) & 0x000F000F000F000Full;
  x = (x | (x << 6))  & 0x0303030303030303ull;
  x = (x | (x << 3))  & 0x1111111111111111ull;
  return x;
}

// ---- merged prep: weight pack + w1a1 + pads + adj bitmask + kcWh MFMA ----
__global__ __launch_bounds__(256) void prep_kernel(
    const int* __restrict__ adj, const float* __restrict__ kc_h,
    const float* __restrict__ W1, const float* __restrict__ E,
    const float* __restrict__ a, const float* __restrict__ rd_w) {
  __shared__ float tshare[4][16];
  int b = blockIdx.x, tid = threadIdx.x;
  if (b < 32) {  // rd_w -> packed B (ct 16 x kt 16)
#pragma unroll
    for (int s2 = 0; s2 < 2; ++s2) {
      int sId = b * 512 + tid + s2 * 256;
      int ct = sId >> 10, rem = sId & 1023;
      int kt = rem >> 6, lane = rem & 63;
      int g = lane >> 4, r = lane & 15;
      const float* src = rd_w + (size_t)(ct * 16 + r) * 512 + kt * 32 + g * 8;
      unsigned short* dst = g_rdw_pk + (size_t)sId * 8;
      cvt_store4(*(const float4*)src, dst);
      cvt_store4(*(const float4*)(src + 4), dst + 4);
    }
  } else if (b < 48) {  // E^T -> packed B
#pragma unroll
    for (int s2 = 0; s2 < 2; ++s2) {
      int sId = (b - 32) * 512 + tid + s2 * 256;
      int ct = sId >> 9, rem = sId & 511;
      int kt = rem >> 6, lane = rem & 63;
      int g = lane >> 4, r = lane & 15;
      int col = ct * 16 + r, k = kt * 32 + g * 8;
      unsigned short* dst = g_ET_pk + (size_t)sId * 8;
      ushort4 o0, o1;
      o0.x = f2bf(E[(k + 0) * 256 + col]); o0.y = f2bf(E[(k + 1) * 256 + col]);
      o0.z = f2bf(E[(k + 2) * 256 + col]); o0.w = f2bf(E[(k + 3) * 256 + col]);
      o1.x = f2bf(E[(k + 4) * 256 + col]); o1.y = f2bf(E[(k + 5) * 256 + col]);
      o1.z = f2bf(E[(k + 6) * 256 + col]); o1.w = f2bf(E[(k + 7) * 256 + col]);
      *(ushort4*)dst = o0; *(ushort4*)(dst + 4) = o1;
    }
  } else if (b == 48) {  // w1a1
    float acc = 0.f;
    for (int q = 0; q < 64; ++q) {
      float4 wv = *(const float4*)(W1 + (size_t)tid * 256 + q * 4);
      float4 a4 = *(const float4*)(a + q * 4);
      acc += wv.x * a4.x + wv.y * a4.y + wv.z * a4.z + wv.w * a4.w;
    }
    g_w1a1[tid] = acc;
  } else if (b == 49) {  // zero ONLY true pad: kt63 fully, kt62 lsub>=32
    for (int idx = tid; idx < 16 * 2 * 512; idx += 256) {
      int ct = idx >> 10, rem = idx & 1023;
      int kt = 62 + (rem >> 9), off = rem & 511;
      if (kt == 63 || off >= 256)
        g_kcWh_pk[((size_t)ct * 64 + kt) * 512 + off] = 0;
    }
  } else if (b < 2550) {  // adj -> bitmask: int4 + 4 ballots + spread
    int w = tid >> 6, lane = tid & 63;
    int row = (b - 50) * 4 + w;
    const int* ap = adj + (size_t)row * N_KC;
#pragma unroll
    for (int it = 0; it < 8; ++it) {
      int c0 = it * 256 + lane * 4;
      int4 v = {0, 0, 0, 0};
      if (c0 < N_KC) v = *(const int4*)(ap + c0);
      unsigned long long m0 = __ballot(v.x > 0);
      unsigned long long m1 = __ballot(v.y > 0);
      unsigned long long m2 = __ballot(v.z > 0);
      unsigned long long m3 = __ballot(v.w > 0);
      if (lane < 4) {
        int sh = lane * 16;
        unsigned long long W = spread4(m0 >> sh) | (spread4(m1 >> sh) << 1) |
                               (spread4(m2 >> sh) << 2) | (spread4(m3 >> sh) << 3);
        g_bm64[(size_t)row * 32 + it * 4 + lane] = W;
      }
    }
  } else {  // kcWh^T via MFMA, B-frags straight from f32 W1; t partials
    int kb = b - 2550;
    int lane = tid & 63, w = tid >> 6;
    int r = lane & 15, g = lane >> 4;
    int j0 = (kb >> 2) * 16;
    int ct = (kb & 3) * 4 + w;
    int col = ct * 16 + r;
    f32x4 acc = {0.f, 0.f, 0.f, 0.f};
    for (int kk = 0; kk < 8; ++kk) {
      int k = kk * 32 + g * 8;
      const float* src = kc_h + (size_t)(j0 + r) * 256 + k;
      float4 x0 = *(const float4*)src, x1 = *(const float4*)(src + 4);
      short8 af = {(short)f2bf(x0.x), (short)f2bf(x0.y), (short)f2bf(x0.z),
                   (short)f2bf(x0.w), (short)f2bf(x1.x), (short)f2bf(x1.y),
                   (short)f2bf(x1.z), (short)f2bf(x1.w)};
      short8 bf = {(short)f2bf(W1[(size_t)(k + 0) * 256 + col]),
                   (short)f2bf(W1[(size_t)(k + 1) * 256 + col]),
                   (short)f2bf(W1[(size_t)(k + 2) * 256 + col]),
                   (short)f2bf(W1[(size_t)(k + 3) * 256 + col]),
                   (short)f2bf(W1[(size_t)(k + 4) * 256 + col]),
                   (short)f2bf(W1[(size_t)(k + 5) * 256 + col]),
                   (short)f2bf(W1[(size_t)(k + 6) * 256 + col]),
                   (short)f2bf(W1[(size_t)(k + 7) * 256 + col])};
      acc = __builtin_amdgcn_mfma_f32_16x16x32_bf16(af, bf, acc, 0, 0, 0);
    }
    // packed store of kcWh^T fragment
    int j = j0 + g * 4;
    int kt = j >> 5, lsub = ((j >> 3) & 3) * 16 + r, sub = (g & 1) * 4;
    ushort4 o;
    o.x = f2bf(acc[0]); o.y = f2bf(acc[1]);
    o.z = f2bf(acc[2]); o.w = f2bf(acc[3]);
    *reinterpret_cast<ushort4*>(
        g_kcWh_pk + ((size_t)ct * 64 + kt) * 512 + lsub * 8 + sub) = o;
    // t partial: reduce this wave's 16 cols, then across the 4 waves via LDS
    float a2v = a[256 + ct * 16 + r];
    float tp[4];
#pragma unroll
    for (int q = 0; q < 4; ++q) tp[q] = acc[q] * a2v;
#pragma unroll
    for (int off = 1; off < 16; off <<= 1)
#pragma unroll
      for (int q = 0; q < 4; ++q) tp[q] += __shfl_xor(tp[q], off, 64);
    if (r == 0)
#pragma unroll
      for (int q = 0; q < 4; ++q) tshare[w][g * 4 + q] = tp[q];
    __syncthreads();
    if (tid < 16)
      g_t_part[kb & 3][j0 + tid] = tshare[0][tid] + tshare[1][tid] +
                                   tshare[2][tid] + tshare[3][tid];
  }
}

// ---- main: TR=32, bitmask P-gen pipeline + fused 3 MFMA GEMMs ----
#define PSTR 136
#define FST 536
__global__ __launch_bounds__(512, 4) void main_kernel(
    const float* __restrict__ exh, const float* __restrict__ rd_b,
    float* __restrict__ out) {
  __shared__ __align__(16) unsigned char smem[50816];
  __shared__ float ds_part[8][32];
  __shared__ float red32[32];
  float* t_s = (float*)smem;                                       // 8320 B
  unsigned long long* bm_s = (unsigned long long*)(smem + 8320);   // 32*34*8
  unsigned short* p_s = (unsigned short*)(smem + 17024);           // [2][32][136]
  unsigned short* exh_pk_s = (unsigned short*)(smem + 34432);      // [2][4096]
  unsigned short* feat_s = (unsigned short*)smem;                  // [32][536] late

  int tid = threadIdx.x, w = tid >> 6, lane = tid & 63;
  int r = lane & 15, g = lane >> 4;
  int i0 = blockIdx.x * 32;
  int mh = w >> 2, kw = w & 3;

  // ---- phase 0: stage t (sum 4 partials), bitmask, exh frags; s ----
  for (int q = tid; q < 520; q += 512) {
    float4 v = {0.f, 0.f, 0.f, 0.f};
    if (q < 500) {
      float4 p0 = ((const float4*)g_t_part[0])[q];
      float4 p1 = ((const float4*)g_t_part[1])[q];
      float4 p2 = ((const float4*)g_t_part[2])[q];
      float4 p3 = ((const float4*)g_t_part[3])[q];
      v.x = p0.x + p1.x + p2.x + p3.x;
      v.y = p0.y + p1.y + p2.y + p3.y;
      v.z = p0.z + p1.z + p2.z + p3.z;
      v.w = p0.w + p1.w + p2.w + p3.w;
    }
    ((float4*)t_s)[q] = v;
  }
  for (int q = tid; q < 32 * 32; q += 512) {
    int rr = q >> 5, wd = q & 31;
    int grow = i0 + rr; grow = grow < N_E ? grow : N_E - 1;
    bm_s[rr * 34 + wd] = g_bm64[(size_t)grow * 32 + wd];
  }
  {
    const float* wsrc = g_w1a1 + w * 32 + g * 8;
    float4 w0 = *(const float4*)wsrc, w1 = *(const float4*)(wsrc + 4);
    float sp[2];
#pragma unroll
    for (int m = 0; m < 2; ++m) {
      int row = i0 + m * 16 + r; row = row < N_E ? row : N_E - 1;
      const float* xsrc = exh + (size_t)row * 256 + w * 32 + g * 8;
      float4 x0 = *(const float4*)xsrc, x1 = *(const float4*)(xsrc + 4);
      unsigned short* dst = exh_pk_s + m * 4096 + w * 512 + lane * 8;
      cvt_store4(x0, dst); cvt_store4(x1, dst + 4);
      sp[m] = x0.x * w0.x + x0.y * w0.y + x0.z * w0.z + x0.w * w0.w +
              x1.x * w1.x + x1.y * w1.y + x1.z * w1.z + x1.w * w1.w;
      sp[m] += __shfl_xor(sp[m], 16, 64);
      sp[m] += __shfl_xor(sp[m], 32, 64);
    }
    if (lane < 16) { ds_part[w][lane] = sp[0]; ds_part[w][16 + lane] = sp[1]; }
  }
  __syncthreads();
  if (tid < 32) {
    float sv = 0.f;
#pragma unroll
    for (int ww = 0; ww < 8; ++ww) sv += ds_part[ww][tid];
    red32[tid] = sv;
  }
  __syncthreads();
  float sv = red32[mh * 16 + r];

  f32x4 accP[2][2] = {{{0.f,0.f,0.f,0.f},{0.f,0.f,0.f,0.f}},
                      {{0.f,0.f,0.f,0.f},{0.f,0.f,0.f,0.f}}};
  f32x4 accE[2][2] = {{{0.f,0.f,0.f,0.f},{0.f,0.f,0.f,0.f}},
                      {{0.f,0.f,0.f,0.f},{0.f,0.f,0.f,0.f}}};
  float dsum = 0.f;

  auto gen = [&](int c) {
    int kk = c * 4 + kw;
    int c0 = kk * 32 + g * 8;
    unsigned mb =
        (unsigned)((bm_s[(mh * 16 + r) * 34 + (c0 >> 6)] >> (c0 & 63)) & 0xFFull);
    float4 t0 = *(const float4*)(t_s + c0);
    float4 t1 = *(const float4*)(t_s + c0 + 4);
    float tv[8] = {t0.x, t0.y, t0.z, t0.w, t1.x, t1.y, t1.z, t1.w};
    unsigned ub[8];
#pragma unroll
    for (int j = 0; j < 8; ++j) {
      float x = sv + tv[j];
      float lx = fmaxf(x, ALPHA * x);
      float pv = ((mb >> j) & 1u) ? __expf(lx) : 0.f;
      dsum += pv;
      ub[j] = __float_as_uint(pv) + 0x8000u;
    }
    int4 pk;
    pk.x = (int)((ub[0] >> 16) | (ub[1] & 0xFFFF0000u));
    pk.y = (int)((ub[2] >> 16) | (ub[3] & 0xFFFF0000u));
    pk.z = (int)((ub[4] >> 16) | (ub[5] & 0xFFFF0000u));
    pk.w = (int)((ub[6] >> 16) | (ub[7] & 0xFFFF0000u));
    *(int4*)(p_s + ((size_t)(c & 1) * 32 + mh * 16 + r) * PSTR + kw * 32 +
             g * 8) = pk;
  };

  auto mfma_chunk = [&](int c) {
    const unsigned short* pb = p_s + (size_t)(c & 1) * 32 * PSTR;
    const unsigned short* bb0 =
        g_kcWh_pk + ((size_t)(w * 2 + 0) * 64 + c * 4) * 512 + lane * 8;
    const unsigned short* bb1 =
        g_kcWh_pk + ((size_t)(w * 2 + 1) * 64 + c * 4) * 512 + lane * 8;
    short8 b0 = *(const short8*)bb0;
    short8 b1 = *(const short8*)bb1;
#pragma unroll
    for (int u = 0; u < 4; ++u) {
      short8 a0 = *(const short8*)(pb + (size_t)r * PSTR + u * 32 + g * 8);
      short8 a1 = *(const short8*)(pb + (size_t)(16 + r) * PSTR + u * 32 + g * 8);
      short8 nb0 = b0, nb1 = b1;
      if (u < 3) {
        nb0 = *(const short8*)(bb0 + (u + 1) * 512);
        nb1 = *(const short8*)(bb1 + (u + 1) * 512);
      }
      accP[0][0] = __builtin_amdgcn_mfma_f32_16x16x32_bf16(a0, b0, accP[0][0], 0, 0, 0);
      accP[1][0] = __builtin_amdgcn_mfma_f32_16x16x32_bf16(a1, b0, accP[1][0], 0, 0, 0);
      accP[0][1] = __builtin_amdgcn_mfma_f32_16x16x32_bf16(a0, b1, accP[0][1], 0, 0, 0);
      accP[1][1] = __builtin_amdgcn_mfma_f32_16x16x32_bf16(a1, b1, accP[1][1], 0, 0, 0);
      b0 = nb0; b1 = nb1;
    }
    if ((c & 1) == 0) {  // fused ex_Eh kt = c/2
      int ke = c >> 1;
      short8 a0 = *(const short8*)(exh_pk_s + ke * 512 + lane * 8);
      short8 a1 = *(const short8*)(exh_pk_s + 4096 + ke * 512 + lane * 8);
#pragma unroll
      for (int n = 0; n < 2; ++n) {
        short8 be = *(const short8*)(g_ET_pk + ((size_t)(w * 2 + n) * 8 + ke) *
                                                   512 + lane * 8);
        accE[0][n] = __builtin_amdgcn_mfma_f32_16x16x32_bf16(a0, be, accE[0][n], 0, 0, 0);
        accE[1][n] = __builtin_amdgcn_mfma_f32_16x16x32_bf16(a1, be, accE[1][n], 0, 0, 0);
      }
    }
  };

  gen(0);
  __syncthreads();
  for (int c = 1; c < 16; ++c) {
    gen(c);
    mfma_chunk(c - 1);
    __syncthreads();
  }
  mfma_chunk(15);

  dsum += __shfl_xor(dsum, 16, 64);
  dsum += __shfl_xor(dsum, 32, 64);
  if (lane < 16) {
    ds_part[w][mh * 16 + lane] = dsum;
    ds_part[w][(1 - mh) * 16 + lane] = 0.f;
  }
  __syncthreads();
  if (tid < 32) {
    float s = 0.f;
#pragma unroll
    for (int ww = 0; ww < 8; ++ww) s += ds_part[ww][tid];
    red32[tid] = 1.f / fmaxf(s, 1e-30f);
  }
  __syncthreads();

  int c0e = w * 32;
#pragma unroll
  for (int m = 0; m < 2; ++m)
#pragma unroll
    for (int n = 0; n < 2; ++n) {
      int col = c0e + n * 16 + r;
#pragma unroll
      for (int q = 0; q < 4; ++q) {
        int row = m * 16 + g * 4 + q;
        float nk = accP[m][n][q] * red32[row];
        feat_s[(size_t)row * FST + col] = f2bf(nk);
        feat_s[(size_t)row * FST + 256 + col] = f2bf(nk * accE[m][n][q]);
      }
    }
  __syncthreads();

  f32x4 accO[2][2] = {{{0.f,0.f,0.f,0.f},{0.f,0.f,0.f,0.f}},
                      {{0.f,0.f,0.f,0.f},{0.f,0.f,0.f,0.f}}};
#pragma unroll
  for (int kt = 0; kt < 16; ++kt) {
    int k = kt * 32 + g * 8;
    short8 a0 = *(const short8*)(feat_s + (size_t)r * FST + k);
    short8 a1 = *(const short8*)(feat_s + (size_t)(16 + r) * FST + k);
#pragma unroll
    for (int n = 0; n < 2; ++n) {
      short8 bf = *(const short8*)(g_rdw_pk + ((size_t)(w * 2 + n) * 16 + kt) *
                                                  512 + lane * 8);
      accO[0][n] = __builtin_amdgcn_mfma_f32_16x16x32_bf16(a0, bf, accO[0][n], 0, 0, 0);
      accO[1][n] = __builtin_amdgcn_mfma_f32_16x16x32_bf16(a1, bf, accO[1][n], 0, 0, 0);
    }
  }
#pragma unroll
  for (int m = 0; m < 2; ++m) {
    if (i0 + m * 16 >= N_E) continue;
#pragma unroll
    for (int n = 0; n < 2; ++n) {
      int col = c0e + n * 16 + r;
      float bias = rd_b[col];
#pragma unroll
      for (int q = 0; q < 4; ++q) {
        int row = i0 + m * 16 + g * 4 + q;
        float x = accO[m][n][q] + bias;
        float res = x > 0.f ? x : (__expf(x) - 1.f);
        out[(size_t)row * 256 + col] = res;
      }
    }
  }
}

extern "C" void kernel_launch(void* const* d_in, const int* in_sizes, int n_in,
                              void* d_out, int out_size, void* d_ws,
                              size_t ws_size, hipStream_t stream) {
  const float* exh  = (const float*)d_in[0];
  const float* kc_h = (const float*)d_in[1];
  const int*   adj  = (const int*)d_in[2];
  const float* W1   = (const float*)d_in[3];
  const float* E    = (const float*)d_in[4];
  const float* a    = (const float*)d_in[5];
  const float* rd_w = (const float*)d_in[6];
  const float* rd_b = (const float*)d_in[7];
  float* out = (float*)d_out;

  prep_kernel<<<3050, 256, 0, stream>>>(adj, kc_h, W1, E, a, rd_w);
  main_kernel<<<(N_E + 31) / 32, 512, 0, stream>>>(exh, rd_b, out);
}